// Round 2
// baseline (538.803 us; speedup 1.0000x reference)
//
#include <hip/hip_runtime.h>
#include <hip/hip_bf16.h>

#define BB 8
#define TT 2048
#define CC 1024
#define HH 64

// ---------------------------------------------------------------------------
// Kernel 1: q/k/v projections.  x:[16384,1024] f32, W:[1024,64] f32 -> f32
// grid (256, 3): 64-row tile per block, y selects {Wq,Wk,Wv}
// ---------------------------------------------------------------------------
__global__ __launch_bounds__(256) void proj_kernel(
    const float* __restrict__ x, const float* __restrict__ Wq,
    const float* __restrict__ Wk, const float* __restrict__ Wv,
    float* __restrict__ q, float* __restrict__ k, float* __restrict__ v)
{
    const int tid = threadIdx.x;
    const int ty = tid >> 4, tx = tid & 15;
    const int r4 = ty * 4, c4b = tx * 4;
    const float* W = (blockIdx.y == 0) ? Wq : (blockIdx.y == 1) ? Wk : Wv;
    float* out = (blockIdx.y == 0) ? q : (blockIdx.y == 1) ? k : v;
    const int r0 = blockIdx.x * 64;

    __shared__ float sx[64][65];   // x tile [row][kk]
    __shared__ float sw[64][65];   // W tile [kk][h]

    float acc[4][4] = {};

    for (int k0 = 0; k0 < CC; k0 += 64) {
        #pragma unroll
        for (int i = 0; i < 4; i++) {
            int f = tid + i * 256;
            int row = f >> 4, c4 = (f & 15) * 4;
            float4 u = *(const float4*)(x + (size_t)(r0 + row) * CC + k0 + c4);
            sx[row][c4 + 0] = u.x; sx[row][c4 + 1] = u.y;
            sx[row][c4 + 2] = u.z; sx[row][c4 + 3] = u.w;
        }
        #pragma unroll
        for (int i = 0; i < 4; i++) {
            int f = tid + i * 256;
            int row = f >> 4, c4 = (f & 15) * 4;
            float4 u = *(const float4*)(W + (size_t)(k0 + row) * HH + c4);
            sw[row][c4 + 0] = u.x; sw[row][c4 + 1] = u.y;
            sw[row][c4 + 2] = u.z; sw[row][c4 + 3] = u.w;
        }
        __syncthreads();
        #pragma unroll 4
        for (int kk = 0; kk < 64; kk++) {
            float a[4], b[4];
            #pragma unroll
            for (int i = 0; i < 4; i++) a[i] = sx[r4 + i][kk];
            #pragma unroll
            for (int j = 0; j < 4; j++) b[j] = sw[kk][c4b + j];
            #pragma unroll
            for (int i = 0; i < 4; i++)
                #pragma unroll
                for (int j = 0; j < 4; j++)
                    acc[i][j] += a[i] * b[j];
        }
        __syncthreads();
    }
    #pragma unroll
    for (int i = 0; i < 4; i++)
        #pragma unroll
        for (int j = 0; j < 4; j++)
            out[(size_t)(r0 + r4 + i) * HH + c4b + j] = acc[i][j];
}

// ---------------------------------------------------------------------------
// Kernel 2: column sums  l[b,s] = sum_{t>=s} exp(q_t . k_s)
// grid (32, 8): 64-column tile per block
// ---------------------------------------------------------------------------
__global__ __launch_bounds__(256) void colsum_kernel(
    const float* __restrict__ q, const float* __restrict__ k,
    float* __restrict__ lsum)
{
    const int tid = threadIdx.x;
    const int ty = tid >> 4, tx = tid & 15;
    const int r4 = ty * 4, c4 = tx * 4;
    const int b = blockIdx.y;
    const int s0 = blockIdx.x * 64;
    const float* qb = q + (size_t)b * TT * HH;
    const float* kb = k + (size_t)b * TT * HH;

    __shared__ float sk[64][65];   // k tile [s'][h]
    __shared__ float sq[64][65];   // q tile [t'][h]
    __shared__ float red[64][17];

    #pragma unroll
    for (int i = 0; i < 4; i++) {
        int f = tid + i * 256;
        int row = f >> 4, cc = (f & 15) * 4;
        float4 u = *(const float4*)(kb + (size_t)(s0 + row) * HH + cc);
        sk[row][cc + 0] = u.x; sk[row][cc + 1] = u.y;
        sk[row][cc + 2] = u.z; sk[row][cc + 3] = u.w;
    }

    float accl[4] = {0.f, 0.f, 0.f, 0.f};

    for (int t0 = s0; t0 < TT; t0 += 64) {
        #pragma unroll
        for (int i = 0; i < 4; i++) {
            int f = tid + i * 256;
            int row = f >> 4, cc = (f & 15) * 4;
            float4 u = *(const float4*)(qb + (size_t)(t0 + row) * HH + cc);
            sq[row][cc + 0] = u.x; sq[row][cc + 1] = u.y;
            sq[row][cc + 2] = u.z; sq[row][cc + 3] = u.w;
        }
        __syncthreads();   // sq ready (and sk on first iter)

        float sc[4][4] = {};
        #pragma unroll 4
        for (int kk = 0; kk < 64; kk++) {
            float a[4], bb[4];
            #pragma unroll
            for (int i = 0; i < 4; i++) a[i] = sq[r4 + i][kk];
            #pragma unroll
            for (int j = 0; j < 4; j++) bb[j] = sk[c4 + j][kk];
            #pragma unroll
            for (int i = 0; i < 4; i++)
                #pragma unroll
                for (int j = 0; j < 4; j++)
                    sc[i][j] += a[i] * bb[j];
        }

        if (t0 == s0) {
            #pragma unroll
            for (int i = 0; i < 4; i++)
                #pragma unroll
                for (int j = 0; j < 4; j++)
                    if (r4 + i >= c4 + j) accl[j] += __expf(sc[i][j]);
        } else {
            #pragma unroll
            for (int i = 0; i < 4; i++)
                #pragma unroll
                for (int j = 0; j < 4; j++)
                    accl[j] += __expf(sc[i][j]);
        }
        __syncthreads();   // done reading sq before overwrite
    }

    #pragma unroll
    for (int j = 0; j < 4; j++) red[c4 + j][ty] = accl[j];
    __syncthreads();
    if (tid < 64) {
        float s = 0.f;
        #pragma unroll
        for (int i = 0; i < 16; i++) s += red[tid][i];
        lsum[(size_t)b * TT + s0 + tid] = s;
    }
}

// ---------------------------------------------------------------------------
// Kernel 3: out[t,h] = sum_{s<=t} exp(q_t.k_s)/l_s * v[s,h]   (f32 output)
// grid (32, 8): 64-row (t) tile per block
// ---------------------------------------------------------------------------
__global__ __launch_bounds__(256) void attn_out_kernel(
    const float* __restrict__ q, const float* __restrict__ k,
    const float* __restrict__ v, const float* __restrict__ lsum,
    float* __restrict__ out)
{
    const int tid = threadIdx.x;
    const int ty = tid >> 4, tx = tid & 15;
    const int r4 = ty * 4, c4 = tx * 4;
    const int b = blockIdx.y;
    const int t0 = blockIdx.x * 64;
    const float* qb = q + (size_t)b * TT * HH;
    const float* kb = k + (size_t)b * TT * HH;
    const float* vb = v + (size_t)b * TT * HH;
    const float* lb = lsum + (size_t)b * TT;

    __shared__ float sq[64][65];    // q tile [t'][h]
    __shared__ float skw[64][65];   // k tile [s'][h], then w tile [t'][s']
    __shared__ float sv[64][65];    // v tile [s'][h]

    #pragma unroll
    for (int i = 0; i < 4; i++) {
        int f = tid + i * 256;
        int row = f >> 4, cc = (f & 15) * 4;
        float4 u = *(const float4*)(qb + (size_t)(t0 + row) * HH + cc);
        sq[row][cc + 0] = u.x; sq[row][cc + 1] = u.y;
        sq[row][cc + 2] = u.z; sq[row][cc + 3] = u.w;
    }

    float acc[4][4] = {};

    for (int s0 = 0; s0 <= t0; s0 += 64) {
        #pragma unroll
        for (int i = 0; i < 4; i++) {
            int f = tid + i * 256;
            int row = f >> 4, cc = (f & 15) * 4;
            float4 u = *(const float4*)(kb + (size_t)(s0 + row) * HH + cc);
            skw[row][cc + 0] = u.x; skw[row][cc + 1] = u.y;
            skw[row][cc + 2] = u.z; skw[row][cc + 3] = u.w;
            float4 w = *(const float4*)(vb + (size_t)(s0 + row) * HH + cc);
            sv[row][cc + 0] = w.x; sv[row][cc + 1] = w.y;
            sv[row][cc + 2] = w.z; sv[row][cc + 3] = w.w;
        }
        __syncthreads();   // k/v tiles ready (and sq on first iter)

        float sc[4][4] = {};
        #pragma unroll 4
        for (int kk = 0; kk < 64; kk++) {
            float a[4], bb[4];
            #pragma unroll
            for (int i = 0; i < 4; i++) a[i] = sq[r4 + i][kk];
            #pragma unroll
            for (int j = 0; j < 4; j++) bb[j] = skw[c4 + j][kk];
            #pragma unroll
            for (int i = 0; i < 4; i++)
                #pragma unroll
                for (int j = 0; j < 4; j++)
                    sc[i][j] += a[i] * bb[j];
        }

        float linv[4], w[4][4];
        #pragma unroll
        for (int j = 0; j < 4; j++) linv[j] = 1.0f / lb[s0 + c4 + j];
        if (t0 == s0) {
            #pragma unroll
            for (int i = 0; i < 4; i++)
                #pragma unroll
                for (int j = 0; j < 4; j++)
                    w[i][j] = (r4 + i >= c4 + j) ? __expf(sc[i][j]) * linv[j] : 0.f;
        } else {
            #pragma unroll
            for (int i = 0; i < 4; i++)
                #pragma unroll
                for (int j = 0; j < 4; j++)
                    w[i][j] = __expf(sc[i][j]) * linv[j];
        }
        __syncthreads();   // all lanes done reading k tile
        #pragma unroll
        for (int i = 0; i < 4; i++)
            #pragma unroll
            for (int j = 0; j < 4; j++)
                skw[r4 + i][c4 + j] = w[i][j];
        __syncthreads();   // w tile ready

        #pragma unroll 4
        for (int ss = 0; ss < 64; ss++) {
            float a[4], bb[4];
            #pragma unroll
            for (int i = 0; i < 4; i++) a[i] = skw[r4 + i][ss];
            #pragma unroll
            for (int j = 0; j < 4; j++) bb[j] = sv[ss][c4 + j];
            #pragma unroll
            for (int i = 0; i < 4; i++)
                #pragma unroll
                for (int j = 0; j < 4; j++)
                    acc[i][j] += a[i] * bb[j];
        }
        __syncthreads();   // done with skw/sv before next overwrite
    }

    #pragma unroll
    for (int i = 0; i < 4; i++)
        #pragma unroll
        for (int j = 0; j < 4; j++)
            out[(size_t)(b * TT + t0 + r4 + i) * HH + c4 + j] = acc[i][j];
}

extern "C" void kernel_launch(void* const* d_in, const int* in_sizes, int n_in,
                              void* d_out, int out_size, void* d_ws, size_t ws_size,
                              hipStream_t stream)
{
    const float* x  = (const float*)d_in[0];
    const float* Wq = (const float*)d_in[1];
    const float* Wk = (const float*)d_in[2];
    const float* Wv = (const float*)d_in[3];
    float* out = (float*)d_out;

    float* q = (float*)d_ws;                       // [8*2048, 64]
    float* k = q + (size_t)BB * TT * HH;
    float* v = k + (size_t)BB * TT * HH;
    float* l = v + (size_t)BB * TT * HH;           // [8, 2048]

    proj_kernel<<<dim3(256, 3), 256, 0, stream>>>(x, Wq, Wk, Wv, q, k, v);
    colsum_kernel<<<dim3(TT / 64, BB), 256, 0, stream>>>(q, k, l);
    attn_out_kernel<<<dim3(TT / 64, BB), 256, 0, stream>>>(q, k, v, l, out);
}

// Round 3
// 295.685 us; speedup vs baseline: 1.8222x; 1.8222x over previous
//
#include <hip/hip_runtime.h>
#include <hip/hip_bf16.h>

#define BB 8
#define TT 2048
#define CC 1024
#define HH 64

typedef unsigned short ushort_t;
typedef __attribute__((ext_vector_type(8))) short bf16x8;
typedef __attribute__((ext_vector_type(4))) float f32x4;

__device__ __forceinline__ float bf2f(ushort_t u) {
    unsigned int x = ((unsigned int)u) << 16;
    return __uint_as_float(x);
}
__device__ __forceinline__ ushort_t f2bf(float f) {
    unsigned int x = __float_as_uint(f);
    unsigned int lsb = (x >> 16) & 1;
    x += 0x7fffu + lsb;   // round-to-nearest-even
    return (ushort_t)(x >> 16);
}

// ---------------------------------------------------------------------------
// Kernel 1: projections. x:[16384,1024] f32, W:[1024,64] f32.
// y=0 -> q_hi/q_lo (bf16 split), y=1 -> k_hi/k_lo, y=2 -> vt (bf16, [b][h][t])
// ---------------------------------------------------------------------------
__global__ __launch_bounds__(256) void proj_kernel(
    const float* __restrict__ x, const float* __restrict__ Wq,
    const float* __restrict__ Wk, const float* __restrict__ Wv,
    ushort_t* __restrict__ qh, ushort_t* __restrict__ ql,
    ushort_t* __restrict__ kh, ushort_t* __restrict__ kl,
    ushort_t* __restrict__ vt)
{
    const int tid = threadIdx.x;
    const int ty = tid >> 4, tx = tid & 15;
    const int r4 = ty * 4, c4b = tx * 4;
    const float* W = (blockIdx.y == 0) ? Wq : (blockIdx.y == 1) ? Wk : Wv;
    const int r0 = blockIdx.x * 64;

    __shared__ float sx[64][65];
    __shared__ float sw[64][65];

    float acc[4][4] = {};

    for (int k0 = 0; k0 < CC; k0 += 64) {
        #pragma unroll
        for (int i = 0; i < 4; i++) {
            int f = tid + i * 256;
            int row = f >> 4, c4 = (f & 15) * 4;
            float4 u = *(const float4*)(x + (size_t)(r0 + row) * CC + k0 + c4);
            sx[row][c4 + 0] = u.x; sx[row][c4 + 1] = u.y;
            sx[row][c4 + 2] = u.z; sx[row][c4 + 3] = u.w;
        }
        #pragma unroll
        for (int i = 0; i < 4; i++) {
            int f = tid + i * 256;
            int row = f >> 4, c4 = (f & 15) * 4;
            float4 u = *(const float4*)(W + (size_t)(k0 + row) * HH + c4);
            sw[row][c4 + 0] = u.x; sw[row][c4 + 1] = u.y;
            sw[row][c4 + 2] = u.z; sw[row][c4 + 3] = u.w;
        }
        __syncthreads();
        #pragma unroll 4
        for (int kk = 0; kk < 64; kk++) {
            float a[4], b[4];
            #pragma unroll
            for (int i = 0; i < 4; i++) a[i] = sx[r4 + i][kk];
            #pragma unroll
            for (int j = 0; j < 4; j++) b[j] = sw[kk][c4b + j];
            #pragma unroll
            for (int i = 0; i < 4; i++)
                #pragma unroll
                for (int j = 0; j < 4; j++)
                    acc[i][j] += a[i] * b[j];
        }
        __syncthreads();
    }

    if (blockIdx.y < 2) {
        ushort_t* hi = (blockIdx.y == 0) ? qh : kh;
        ushort_t* lo = (blockIdx.y == 0) ? ql : kl;
        #pragma unroll
        for (int i = 0; i < 4; i++) {
            ushort_t hv[4], lv[4];
            #pragma unroll
            for (int j = 0; j < 4; j++) {
                float a = acc[i][j];
                ushort_t h = f2bf(a);
                hv[j] = h;
                lv[j] = f2bf(a - bf2f(h));
            }
            size_t off = (size_t)(r0 + r4 + i) * HH + c4b;
            *(ushort4*)(hi + off) = make_ushort4(hv[0], hv[1], hv[2], hv[3]);
            *(ushort4*)(lo + off) = make_ushort4(lv[0], lv[1], lv[2], lv[3]);
        }
    } else {
        // transpose 64x64 v-tile through LDS (reuse sw), emit vt[b][h][t] bf16
        #pragma unroll
        for (int i = 0; i < 4; i++)
            #pragma unroll
            for (int j = 0; j < 4; j++)
                sw[c4b + j][r4 + i] = acc[i][j];
        __syncthreads();
        const int b = r0 >> 11;          // 2048 rows per batch
        const int tloc = r0 & 2047;
        #pragma unroll
        for (int u = 0; u < 4; u++) {
            int f = tid * 4 + u;
            int h = f >> 4, t4 = (f & 15) * 4;
            ushort_t w0 = f2bf(sw[h][t4 + 0]);
            ushort_t w1 = f2bf(sw[h][t4 + 1]);
            ushort_t w2 = f2bf(sw[h][t4 + 2]);
            ushort_t w3 = f2bf(sw[h][t4 + 3]);
            *(ushort4*)(vt + (size_t)(b * HH + h) * TT + tloc + t4) =
                make_ushort4(w0, w1, w2, w3);
        }
    }
}

// ---------------------------------------------------------------------------
// Kernel 2: l[b,s] = sum_{t>=s} exp(q_t . k_s) via split-bf16 MFMA.
// grid (16 tc, 16 st, 8 b), active tc>=st. Block 128t x 128s, wave 64x64.
// ---------------------------------------------------------------------------
__global__ __launch_bounds__(256) void colsum_mfma(
    const ushort_t* __restrict__ qh, const ushort_t* __restrict__ ql,
    const ushort_t* __restrict__ kh, const ushort_t* __restrict__ kl,
    float* __restrict__ lsum)
{
    const int tc = blockIdx.x, st = blockIdx.y, b = blockIdx.z;
    if (tc < st) return;
    const int tid = threadIdx.x;
    const int lane = tid & 63, wid = tid >> 6;
    const int quad = lane >> 4, l15 = lane & 15;
    const int wy = wid >> 1, wx = wid & 1;
    const int t_base = tc * 128 + wy * 64;
    const int s_base = st * 128 + wx * 64;
    if (t_base < s_base) return;                 // fully-masked wave tile
    const bool needMask = (t_base == s_base);

    const size_t boff = (size_t)b * TT * HH;
    const ushort_t* qhb = qh + boff;
    const ushort_t* qlb = ql + boff;
    const ushort_t* khb = kh + boff;
    const ushort_t* klb = kl + boff;

    f32x4 acc[4][4];
    #pragma unroll
    for (int mt = 0; mt < 4; mt++)
        #pragma unroll
        for (int nt = 0; nt < 4; nt++)
            acc[mt][nt] = (f32x4){0.f, 0.f, 0.f, 0.f};

    bf16x8 bH[4][2], bL[4][2];
    #pragma unroll
    for (int nt = 0; nt < 4; nt++)
        #pragma unroll
        for (int ks = 0; ks < 2; ks++) {
            size_t off = (size_t)(s_base + nt * 16 + l15) * HH + ks * 32 + quad * 8;
            bH[nt][ks] = *(const bf16x8*)(khb + off);
            bL[nt][ks] = *(const bf16x8*)(klb + off);
        }

    #pragma unroll
    for (int mt = 0; mt < 4; mt++) {
        bf16x8 aH[2], aL[2];
        #pragma unroll
        for (int ks = 0; ks < 2; ks++) {
            size_t off = (size_t)(t_base + mt * 16 + l15) * HH + ks * 32 + quad * 8;
            aH[ks] = *(const bf16x8*)(qhb + off);
            aL[ks] = *(const bf16x8*)(qlb + off);
        }
        #pragma unroll
        for (int nt = 0; nt < 4; nt++)
            #pragma unroll
            for (int ks = 0; ks < 2; ks++) {
                acc[mt][nt] = __builtin_amdgcn_mfma_f32_16x16x32_bf16(aL[ks], bH[nt][ks], acc[mt][nt], 0, 0, 0);
                acc[mt][nt] = __builtin_amdgcn_mfma_f32_16x16x32_bf16(aH[ks], bL[nt][ks], acc[mt][nt], 0, 0, 0);
                acc[mt][nt] = __builtin_amdgcn_mfma_f32_16x16x32_bf16(aH[ks], bH[nt][ks], acc[mt][nt], 0, 0, 0);
            }
    }

    float cs[4] = {0.f, 0.f, 0.f, 0.f};
    #pragma unroll
    for (int mt = 0; mt < 4; mt++)
        #pragma unroll
        for (int nt = 0; nt < 4; nt++)
            #pragma unroll
            for (int r = 0; r < 4; r++) {
                float e = __expf(acc[mt][nt][r]);
                if (needMask) {
                    int t = t_base + mt * 16 + quad * 4 + r;
                    int s = s_base + nt * 16 + l15;
                    if (t < s) e = 0.f;
                }
                cs[nt] += e;
            }
    #pragma unroll
    for (int nt = 0; nt < 4; nt++) {
        float v = cs[nt];
        v += __shfl_xor(v, 16);
        v += __shfl_xor(v, 32);
        if (quad == 0)
            atomicAdd(lsum + (size_t)b * TT + s_base + nt * 16 + l15, v);
    }
}

// ---------------------------------------------------------------------------
// Kernel 3: out[t,h] = sum_{s<=t} exp(q_t.k_s)/l_s * v[s,h] via MFMA.
// grid (32 pairs, 8 b). Block handles t-tiles p and 63-p (32 rows each).
// 4 waves, each owns a 64-wide s-chunk per group.
// ---------------------------------------------------------------------------
__global__ __launch_bounds__(256) void attn_mfma(
    const ushort_t* __restrict__ qh, const ushort_t* __restrict__ ql,
    const ushort_t* __restrict__ kh, const ushort_t* __restrict__ kl,
    const ushort_t* __restrict__ vt, const float* __restrict__ lsum,
    float* __restrict__ out)
{
    const int p = blockIdx.x, b = blockIdx.y;
    const int tid = threadIdx.x;
    const int lane = tid & 63, wid = tid >> 6;
    const int quad = lane >> 4, l15 = lane & 15;

    __shared__ __align__(16) float red[4][2048];     // 32 KB; sP overlaps it
    ushort_t* sP = (ushort_t*)red + wid * (32 * 72); // wave-private 32x72 bf16

    const size_t boff = (size_t)b * TT * HH;
    const ushort_t* qhb = qh + boff;
    const ushort_t* qlb = ql + boff;
    const ushort_t* khb = kh + boff;
    const ushort_t* klb = kl + boff;
    const ushort_t* vtb = vt + boff;                 // [64][2048]
    const float* lb = lsum + (size_t)b * TT;

    #pragma unroll
    for (int half = 0; half < 2; half++) {
        const int tileI = half ? (63 - p) : p;
        const int t0 = tileI * 32;

        // q fragments for this tile (constant across s-chunks)
        bf16x8 aH[2][2], aL[2][2];
        #pragma unroll
        for (int mt = 0; mt < 2; mt++)
            #pragma unroll
            for (int ks = 0; ks < 2; ks++) {
                size_t off = (size_t)(t0 + mt * 16 + l15) * HH + ks * 32 + quad * 8;
                aH[mt][ks] = *(const bf16x8*)(qhb + off);
                aL[mt][ks] = *(const bf16x8*)(qlb + off);
            }

        f32x4 oacc[2][4];
        #pragma unroll
        for (int mt = 0; mt < 2; mt++)
            #pragma unroll
            for (int nt = 0; nt < 4; nt++)
                oacc[mt][nt] = (f32x4){0.f, 0.f, 0.f, 0.f};

        const int cnum = (t0 >> 6) + 1;
        const int groups = (cnum + 3) >> 2;
        for (int g = 0; g < groups; g++) {
            const int s0 = (g * 4 + wid) * 64;
            if (s0 <= t0 + 31) {
                // ---- S = Q K^T (split bf16, fp32 acc) ----
                f32x4 sacc[2][4];
                #pragma unroll
                for (int mt = 0; mt < 2; mt++)
                    #pragma unroll
                    for (int nt = 0; nt < 4; nt++)
                        sacc[mt][nt] = (f32x4){0.f, 0.f, 0.f, 0.f};
                #pragma unroll
                for (int nt = 0; nt < 4; nt++) {
                    bf16x8 bH2[2], bL2[2];
                    #pragma unroll
                    for (int ks = 0; ks < 2; ks++) {
                        size_t off = (size_t)(s0 + nt * 16 + l15) * HH + ks * 32 + quad * 8;
                        bH2[ks] = *(const bf16x8*)(khb + off);
                        bL2[ks] = *(const bf16x8*)(klb + off);
                    }
                    #pragma unroll
                    for (int mt = 0; mt < 2; mt++)
                        #pragma unroll
                        for (int ks = 0; ks < 2; ks++) {
                            sacc[mt][nt] = __builtin_amdgcn_mfma_f32_16x16x32_bf16(aL[mt][ks], bH2[ks], sacc[mt][nt], 0, 0, 0);
                            sacc[mt][nt] = __builtin_amdgcn_mfma_f32_16x16x32_bf16(aH[mt][ks], bL2[ks], sacc[mt][nt], 0, 0, 0);
                            sacc[mt][nt] = __builtin_amdgcn_mfma_f32_16x16x32_bf16(aH[mt][ks], bH2[ks], sacc[mt][nt], 0, 0, 0);
                        }
                }
                // ---- P = exp(S)/l_s -> bf16 -> wave-private LDS ----
                const bool msk = (s0 + 63 > t0);
                float linv[4];
                #pragma unroll
                for (int nt = 0; nt < 4; nt++)
                    linv[nt] = 1.0f / lb[s0 + nt * 16 + l15];
                #pragma unroll
                for (int mt = 0; mt < 2; mt++)
                    #pragma unroll
                    for (int nt = 0; nt < 4; nt++)
                        #pragma unroll
                        for (int r = 0; r < 4; r++) {
                            float e = __expf(sacc[mt][nt][r]);
                            if (msk) {
                                int t = t0 + mt * 16 + quad * 4 + r;
                                int s = s0 + nt * 16 + l15;
                                if (t < s) e = 0.f;
                            }
                            sP[(mt * 16 + quad * 4 + r) * 72 + nt * 16 + l15] =
                                f2bf(e * linv[nt]);
                        }
                // ---- O += P V  (A from LDS, B from vt global) ----
                bf16x8 pa[2][2];
                #pragma unroll
                for (int mt = 0; mt < 2; mt++)
                    #pragma unroll
                    for (int ks = 0; ks < 2; ks++)
                        pa[mt][ks] = *(const bf16x8*)(sP + (mt * 16 + l15) * 72 + ks * 32 + quad * 8);
                #pragma unroll
                for (int nt = 0; nt < 4; nt++)
                    #pragma unroll
                    for (int ks = 0; ks < 2; ks++) {
                        bf16x8 vb = *(const bf16x8*)(vtb + (size_t)(nt * 16 + l15) * TT + s0 + ks * 32 + quad * 8);
                        #pragma unroll
                        for (int mt = 0; mt < 2; mt++)
                            oacc[mt][nt] = __builtin_amdgcn_mfma_f32_16x16x32_bf16(pa[mt][ks], vb, oacc[mt][nt], 0, 0, 0);
                    }
            }
        }
        // ---- cross-wave reduction of the 32x64 out tile ----
        __syncthreads();   // sP dead everywhere before red overwrite
        #pragma unroll
        for (int mt = 0; mt < 2; mt++)
            #pragma unroll
            for (int nt = 0; nt < 4; nt++)
                #pragma unroll
                for (int r = 0; r < 4; r++)
                    red[wid][(mt * 16 + quad * 4 + r) * 64 + nt * 16 + l15] =
                        oacc[mt][nt][r];
        __syncthreads();
        for (int e = tid; e < 2048; e += 256) {
            float s_ = red[0][e] + red[1][e] + red[2][e] + red[3][e];
            out[(size_t)(b * TT + t0 + (e >> 6)) * HH + (e & 63)] = s_;
        }
        __syncthreads();   // before next tile reuses LDS
    }
}

extern "C" void kernel_launch(void* const* d_in, const int* in_sizes, int n_in,
                              void* d_out, int out_size, void* d_ws, size_t ws_size,
                              hipStream_t stream)
{
    const float* x  = (const float*)d_in[0];
    const float* Wq = (const float*)d_in[1];
    const float* Wk = (const float*)d_in[2];
    const float* Wv = (const float*)d_in[3];
    float* out = (float*)d_out;

    const size_t N = (size_t)BB * TT * HH;     // 1,048,576 elements
    ushort_t* qh = (ushort_t*)d_ws;
    ushort_t* ql = qh + N;
    ushort_t* kh = ql + N;
    ushort_t* kl = kh + N;
    ushort_t* vt = kl + N;                     // [b][64][2048]
    float* lsum = (float*)(vt + N);            // [8][2048]

    hipMemsetAsync(lsum, 0, (size_t)BB * TT * sizeof(float), stream);
    proj_kernel<<<dim3(256, 3), 256, 0, stream>>>(x, Wq, Wk, Wv, qh, ql, kh, kl, vt);
    colsum_mfma<<<dim3(16, 16, BB), 256, 0, stream>>>(qh, ql, kh, kl, lsum);
    attn_mfma<<<dim3(32, BB), 256, 0, stream>>>(qh, ql, kh, kl, vt, lsum, out);
}

// Round 4
// 287.566 us; speedup vs baseline: 1.8737x; 1.0282x over previous
//
#include <hip/hip_runtime.h>
#include <hip/hip_bf16.h>

#define BB 8
#define TT 2048
#define CC 1024
#define HH 64

typedef unsigned short ushort_t;
typedef __attribute__((ext_vector_type(8))) short bf16x8;
typedef __attribute__((ext_vector_type(4))) float f32x4;

__device__ __forceinline__ float bf2f(ushort_t u) {
    unsigned int x = ((unsigned int)u) << 16;
    return __uint_as_float(x);
}
__device__ __forceinline__ ushort_t f2bf(float f) {
    unsigned int x = __float_as_uint(f);
    unsigned int lsb = (x >> 16) & 1;
    x += 0x7fffu + lsb;   // round-to-nearest-even
    return (ushort_t)(x >> 16);
}

// ---------------------------------------------------------------------------
// Kernel 0: split + transpose W.  W:[1024][64] f32 -> wt{h,l}:[3][64][1024] bf16
// grid 192 x 256: one (mat,c,h4) tuple per thread
// ---------------------------------------------------------------------------
__global__ __launch_bounds__(256) void wsplit_kernel(
    const float* __restrict__ Wq, const float* __restrict__ Wk,
    const float* __restrict__ Wv,
    ushort_t* __restrict__ wth, ushort_t* __restrict__ wtl)
{
    int idx = blockIdx.x * 256 + threadIdx.x;      // [0, 49152)
    int mat = idx >> 14;                           // 16384 tuples per mat
    int rem = idx & 16383;
    int c = rem >> 4;
    int h4 = (rem & 15) * 4;
    const float* W = (mat == 0) ? Wq : (mat == 1) ? Wk : Wv;
    float4 u = *(const float4*)(W + (size_t)c * HH + h4);
    float vals[4] = {u.x, u.y, u.z, u.w};
    #pragma unroll
    for (int j = 0; j < 4; j++) {
        ushort_t h = f2bf(vals[j]);
        ushort_t l = f2bf(vals[j] - bf2f(h));
        size_t off = ((size_t)mat * HH + h4 + j) * CC + c;
        wth[off] = h;
        wtl[off] = l;
    }
}

// ---------------------------------------------------------------------------
// Kernel 1: fused q/k/v projection via split-bf16 MFMA. One pass over x.
// grid 256 x 256: block = 64 rows, wave = 16 rows. q,k split hi/lo; v -> vt.
// ---------------------------------------------------------------------------
__global__ __launch_bounds__(256) void proj_mfma(
    const float* __restrict__ x,
    const ushort_t* __restrict__ wth, const ushort_t* __restrict__ wtl,
    ushort_t* __restrict__ qh, ushort_t* __restrict__ ql,
    ushort_t* __restrict__ kh, ushort_t* __restrict__ kl,
    ushort_t* __restrict__ vt)
{
    const int tid = threadIdx.x;
    const int lane = tid & 63, wid = tid >> 6;
    const int quad = lane >> 4, l15 = lane & 15;
    const int t0g = blockIdx.x * 64;
    const int trow = t0g + wid * 16 + l15;

    __shared__ float sq_[64][68];
    __shared__ float sk_[64][68];
    __shared__ float sv_[64][68];

    f32x4 acc[3][4];
    #pragma unroll
    for (int m = 0; m < 3; m++)
        #pragma unroll
        for (int nt = 0; nt < 4; nt++)
            acc[m][nt] = (f32x4){0.f, 0.f, 0.f, 0.f};

    const float* xrow = x + (size_t)trow * CC;

    #pragma unroll 2
    for (int kc = 0; kc < 32; kc++) {
        const int c0 = kc * 32 + quad * 8;
        float4 u0 = *(const float4*)(xrow + c0);
        float4 u1 = *(const float4*)(xrow + c0 + 4);
        float xv[8] = {u0.x, u0.y, u0.z, u0.w, u1.x, u1.y, u1.z, u1.w};
        bf16x8 xh_, xl_;
        #pragma unroll
        for (int j = 0; j < 8; j++) {
            ushort_t h = f2bf(xv[j]);
            xh_[j] = (short)h;
            xl_[j] = (short)f2bf(xv[j] - bf2f(h));
        }
        #pragma unroll
        for (int mat = 0; mat < 3; mat++)
            #pragma unroll
            for (int nt = 0; nt < 4; nt++) {
                size_t off = ((size_t)mat * HH + nt * 16 + l15) * CC + c0;
                bf16x8 bh = *(const bf16x8*)(wth + off);
                if (mat < 2) {
                    bf16x8 bl = *(const bf16x8*)(wtl + off);
                    acc[mat][nt] = __builtin_amdgcn_mfma_f32_16x16x32_bf16(xl_, bh, acc[mat][nt], 0, 0, 0);
                    acc[mat][nt] = __builtin_amdgcn_mfma_f32_16x16x32_bf16(xh_, bl, acc[mat][nt], 0, 0, 0);
                }
                acc[mat][nt] = __builtin_amdgcn_mfma_f32_16x16x32_bf16(xh_, bh, acc[mat][nt], 0, 0, 0);
            }
    }

    // dump C-tiles to LDS (row = quad*4+r, col = nt*16+l15)
    #pragma unroll
    for (int nt = 0; nt < 4; nt++)
        #pragma unroll
        for (int r = 0; r < 4; r++) {
            int row = wid * 16 + quad * 4 + r;
            int col = nt * 16 + l15;
            sq_[row][col] = acc[0][nt][r];
            sk_[row][col] = acc[1][nt][r];
            sv_[row][col] = acc[2][nt][r];
        }
    __syncthreads();

    // q,k: split hi/lo, row-major vectorized writes
    #pragma unroll
    for (int i = 0; i < 4; i++) {
        int f = tid + i * 256;
        int row = f >> 4, c4 = (f & 15) * 4;
        size_t off = (size_t)(t0g + row) * HH + c4;
        ushort_t hv[4], lv[4];
        #pragma unroll
        for (int j = 0; j < 4; j++) {
            float a = sq_[row][c4 + j];
            hv[j] = f2bf(a);
            lv[j] = f2bf(a - bf2f(hv[j]));
        }
        *(ushort4*)(qh + off) = make_ushort4(hv[0], hv[1], hv[2], hv[3]);
        *(ushort4*)(ql + off) = make_ushort4(lv[0], lv[1], lv[2], lv[3]);
        #pragma unroll
        for (int j = 0; j < 4; j++) {
            float a = sk_[row][c4 + j];
            hv[j] = f2bf(a);
            lv[j] = f2bf(a - bf2f(hv[j]));
        }
        *(ushort4*)(kh + off) = make_ushort4(hv[0], hv[1], hv[2], hv[3]);
        *(ushort4*)(kl + off) = make_ushort4(lv[0], lv[1], lv[2], lv[3]);
    }

    // v: transposed bf16 write -> vt[b][h][t]
    const int b = t0g >> 11, tloc = t0g & 2047;
    #pragma unroll
    for (int i = 0; i < 4; i++) {
        int f = tid + i * 256;
        int h = f >> 4, t4 = (f & 15) * 4;
        ushort4 w = make_ushort4(f2bf(sv_[t4 + 0][h]), f2bf(sv_[t4 + 1][h]),
                                 f2bf(sv_[t4 + 2][h]), f2bf(sv_[t4 + 3][h]));
        *(ushort4*)(vt + ((size_t)b * HH + h) * TT + tloc + t4) = w;
    }
}

// ---------------------------------------------------------------------------
// Kernel 2: l[b,s] = sum_{t>=s} exp(q_t . k_s) via split-bf16 MFMA.
// grid (16 tc, 16 st, 8 b), active tc>=st. Block 128t x 128s, wave 64x64.
// ---------------------------------------------------------------------------
__global__ __launch_bounds__(256) void colsum_mfma(
    const ushort_t* __restrict__ qh, const ushort_t* __restrict__ ql,
    const ushort_t* __restrict__ kh, const ushort_t* __restrict__ kl,
    float* __restrict__ lsum)
{
    const int tc = blockIdx.x, st = blockIdx.y, b = blockIdx.z;
    if (tc < st) return;
    const int tid = threadIdx.x;
    const int lane = tid & 63, wid = tid >> 6;
    const int quad = lane >> 4, l15 = lane & 15;
    const int wy = wid >> 1, wx = wid & 1;
    const int t_base = tc * 128 + wy * 64;
    const int s_base = st * 128 + wx * 64;
    if (t_base < s_base) return;                 // fully-masked wave tile
    const bool needMask = (t_base == s_base);

    const size_t boff = (size_t)b * TT * HH;
    const ushort_t* qhb = qh + boff;
    const ushort_t* qlb = ql + boff;
    const ushort_t* khb = kh + boff;
    const ushort_t* klb = kl + boff;

    f32x4 acc[4][4];
    #pragma unroll
    for (int mt = 0; mt < 4; mt++)
        #pragma unroll
        for (int nt = 0; nt < 4; nt++)
            acc[mt][nt] = (f32x4){0.f, 0.f, 0.f, 0.f};

    bf16x8 bH[4][2], bL[4][2];
    #pragma unroll
    for (int nt = 0; nt < 4; nt++)
        #pragma unroll
        for (int ks = 0; ks < 2; ks++) {
            size_t off = (size_t)(s_base + nt * 16 + l15) * HH + ks * 32 + quad * 8;
            bH[nt][ks] = *(const bf16x8*)(khb + off);
            bL[nt][ks] = *(const bf16x8*)(klb + off);
        }

    #pragma unroll
    for (int mt = 0; mt < 4; mt++) {
        bf16x8 aH[2], aL[2];
        #pragma unroll
        for (int ks = 0; ks < 2; ks++) {
            size_t off = (size_t)(t_base + mt * 16 + l15) * HH + ks * 32 + quad * 8;
            aH[ks] = *(const bf16x8*)(qhb + off);
            aL[ks] = *(const bf16x8*)(qlb + off);
        }
        #pragma unroll
        for (int nt = 0; nt < 4; nt++)
            #pragma unroll
            for (int ks = 0; ks < 2; ks++) {
                acc[mt][nt] = __builtin_amdgcn_mfma_f32_16x16x32_bf16(aL[ks], bH[nt][ks], acc[mt][nt], 0, 0, 0);
                acc[mt][nt] = __builtin_amdgcn_mfma_f32_16x16x32_bf16(aH[ks], bL[nt][ks], acc[mt][nt], 0, 0, 0);
                acc[mt][nt] = __builtin_amdgcn_mfma_f32_16x16x32_bf16(aH[ks], bH[nt][ks], acc[mt][nt], 0, 0, 0);
            }
    }

    float cs[4] = {0.f, 0.f, 0.f, 0.f};
    #pragma unroll
    for (int mt = 0; mt < 4; mt++)
        #pragma unroll
        for (int nt = 0; nt < 4; nt++)
            #pragma unroll
            for (int r = 0; r < 4; r++) {
                float e = __expf(acc[mt][nt][r]);
                if (needMask) {
                    int t = t_base + mt * 16 + quad * 4 + r;
                    int s = s_base + nt * 16 + l15;
                    if (t < s) e = 0.f;
                }
                cs[nt] += e;
            }
    #pragma unroll
    for (int nt = 0; nt < 4; nt++) {
        float v = cs[nt];
        v += __shfl_xor(v, 16);
        v += __shfl_xor(v, 32);
        if (quad == 0)
            atomicAdd(lsum + (size_t)b * TT + s_base + nt * 16 + l15, v);
    }
}

// ---------------------------------------------------------------------------
// Kernel 3: out[t,h] = sum_{s<=t} exp(q_t.k_s)/l_s * v[s,h] via MFMA.
// grid (32 pairs, 8 b). Block handles t-tiles p and 63-p (32 rows each).
// ---------------------------------------------------------------------------
__global__ __launch_bounds__(256) void attn_mfma(
    const ushort_t* __restrict__ qh, const ushort_t* __restrict__ ql,
    const ushort_t* __restrict__ kh, const ushort_t* __restrict__ kl,
    const ushort_t* __restrict__ vt, const float* __restrict__ lsum,
    float* __restrict__ out)
{
    const int p = blockIdx.x, b = blockIdx.y;
    const int tid = threadIdx.x;
    const int lane = tid & 63, wid = tid >> 6;
    const int quad = lane >> 4, l15 = lane & 15;

    __shared__ __align__(16) float red[4][2048];     // 32 KB; sP overlaps it
    ushort_t* sP = (ushort_t*)red + wid * (32 * 72); // wave-private 32x72 bf16

    const size_t boff = (size_t)b * TT * HH;
    const ushort_t* qhb = qh + boff;
    const ushort_t* qlb = ql + boff;
    const ushort_t* khb = kh + boff;
    const ushort_t* klb = kl + boff;
    const ushort_t* vtb = vt + boff;                 // [64][2048]
    const float* lb = lsum + (size_t)b * TT;

    #pragma unroll
    for (int half = 0; half < 2; half++) {
        const int tileI = half ? (63 - p) : p;
        const int t0 = tileI * 32;

        bf16x8 aH[2][2], aL[2][2];
        #pragma unroll
        for (int mt = 0; mt < 2; mt++)
            #pragma unroll
            for (int ks = 0; ks < 2; ks++) {
                size_t off = (size_t)(t0 + mt * 16 + l15) * HH + ks * 32 + quad * 8;
                aH[mt][ks] = *(const bf16x8*)(qhb + off);
                aL[mt][ks] = *(const bf16x8*)(qlb + off);
            }

        f32x4 oacc[2][4];
        #pragma unroll
        for (int mt = 0; mt < 2; mt++)
            #pragma unroll
            for (int nt = 0; nt < 4; nt++)
                oacc[mt][nt] = (f32x4){0.f, 0.f, 0.f, 0.f};

        const int cnum = (t0 >> 6) + 1;
        const int groups = (cnum + 3) >> 2;
        for (int g = 0; g < groups; g++) {
            const int s0 = (g * 4 + wid) * 64;
            if (s0 <= t0 + 31) {
                f32x4 sacc[2][4];
                #pragma unroll
                for (int mt = 0; mt < 2; mt++)
                    #pragma unroll
                    for (int nt = 0; nt < 4; nt++)
                        sacc[mt][nt] = (f32x4){0.f, 0.f, 0.f, 0.f};
                #pragma unroll
                for (int nt = 0; nt < 4; nt++) {
                    bf16x8 bH2[2], bL2[2];
                    #pragma unroll
                    for (int ks = 0; ks < 2; ks++) {
                        size_t off = (size_t)(s0 + nt * 16 + l15) * HH + ks * 32 + quad * 8;
                        bH2[ks] = *(const bf16x8*)(khb + off);
                        bL2[ks] = *(const bf16x8*)(klb + off);
                    }
                    #pragma unroll
                    for (int mt = 0; mt < 2; mt++)
                        #pragma unroll
                        for (int ks = 0; ks < 2; ks++) {
                            sacc[mt][nt] = __builtin_amdgcn_mfma_f32_16x16x32_bf16(aL[mt][ks], bH2[ks], sacc[mt][nt], 0, 0, 0);
                            sacc[mt][nt] = __builtin_amdgcn_mfma_f32_16x16x32_bf16(aH[mt][ks], bL2[ks], sacc[mt][nt], 0, 0, 0);
                            sacc[mt][nt] = __builtin_amdgcn_mfma_f32_16x16x32_bf16(aH[mt][ks], bH2[ks], sacc[mt][nt], 0, 0, 0);
                        }
                }
                const bool msk = (s0 + 63 > t0);
                float linv[4];
                #pragma unroll
                for (int nt = 0; nt < 4; nt++)
                    linv[nt] = 1.0f / lb[s0 + nt * 16 + l15];
                #pragma unroll
                for (int mt = 0; mt < 2; mt++)
                    #pragma unroll
                    for (int nt = 0; nt < 4; nt++)
                        #pragma unroll
                        for (int r = 0; r < 4; r++) {
                            float e = __expf(sacc[mt][nt][r]);
                            if (msk) {
                                int t = t0 + mt * 16 + quad * 4 + r;
                                int s = s0 + nt * 16 + l15;
                                if (t < s) e = 0.f;
                            }
                            sP[(mt * 16 + quad * 4 + r) * 72 + nt * 16 + l15] =
                                f2bf(e * linv[nt]);
                        }
                bf16x8 pa[2][2];
                #pragma unroll
                for (int mt = 0; mt < 2; mt++)
                    #pragma unroll
                    for (int ks = 0; ks < 2; ks++)
                        pa[mt][ks] = *(const bf16x8*)(sP + (mt * 16 + l15) * 72 + ks * 32 + quad * 8);
                #pragma unroll
                for (int nt = 0; nt < 4; nt++)
                    #pragma unroll
                    for (int ks = 0; ks < 2; ks++) {
                        bf16x8 vb = *(const bf16x8*)(vtb + (size_t)(nt * 16 + l15) * TT + s0 + ks * 32 + quad * 8);
                        #pragma unroll
                        for (int mt = 0; mt < 2; mt++)
                            oacc[mt][nt] = __builtin_amdgcn_mfma_f32_16x16x32_bf16(pa[mt][ks], vb, oacc[mt][nt], 0, 0, 0);
                    }
            }
        }
        __syncthreads();
        #pragma unroll
        for (int mt = 0; mt < 2; mt++)
            #pragma unroll
            for (int nt = 0; nt < 4; nt++)
                #pragma unroll
                for (int r = 0; r < 4; r++)
                    red[wid][(mt * 16 + quad * 4 + r) * 64 + nt * 16 + l15] =
                        oacc[mt][nt][r];
        __syncthreads();
        for (int e = tid; e < 2048; e += 256) {
            float s_ = red[0][e] + red[1][e] + red[2][e] + red[3][e];
            out[(size_t)(b * TT + t0 + (e >> 6)) * HH + (e & 63)] = s_;
        }
        __syncthreads();
    }
}

extern "C" void kernel_launch(void* const* d_in, const int* in_sizes, int n_in,
                              void* d_out, int out_size, void* d_ws, size_t ws_size,
                              hipStream_t stream)
{
    const float* x  = (const float*)d_in[0];
    const float* Wq = (const float*)d_in[1];
    const float* Wk = (const float*)d_in[2];
    const float* Wv = (const float*)d_in[3];
    float* out = (float*)d_out;

    const size_t N = (size_t)BB * TT * HH;     // 1,048,576 elements
    ushort_t* qh = (ushort_t*)d_ws;
    ushort_t* ql = qh + N;
    ushort_t* kh = ql + N;
    ushort_t* kl = kh + N;
    ushort_t* vt = kl + N;                     // [b][64][2048]
    float* lsum = (float*)(vt + N);            // [8][2048]
    ushort_t* wth = (ushort_t*)(lsum + (size_t)BB * TT);   // [3][64][1024]
    ushort_t* wtl = wth + (size_t)3 * HH * CC;

    hipMemsetAsync(lsum, 0, (size_t)BB * TT * sizeof(float), stream);
    wsplit_kernel<<<dim3(192), 256, 0, stream>>>(Wq, Wk, Wv, wth, wtl);
    proj_mfma<<<dim3(256), 256, 0, stream>>>(x, wth, wtl, qh, ql, kh, kl, vt);
    colsum_mfma<<<dim3(16, 16, BB), 256, 0, stream>>>(qh, ql, kh, kl, lsum);
    attn_mfma<<<dim3(32, BB), 256, 0, stream>>>(qh, ql, kh, kl, vt, lsum, out);
}

// Round 5
// 235.849 us; speedup vs baseline: 2.2845x; 1.2193x over previous
//
#include <hip/hip_runtime.h>
#include <hip/hip_bf16.h>

#define BB 8
#define TT 2048
#define CC 1024
#define HH 64
#define NTRI 528   // 32*33/2 triangular 64x64 tiles per batch

typedef unsigned short ushort_t;
typedef __attribute__((ext_vector_type(8))) short bf16x8;
typedef __attribute__((ext_vector_type(4))) float f32x4;

__device__ __forceinline__ float bf2f(ushort_t u) {
    unsigned int x = ((unsigned int)u) << 16;
    return __uint_as_float(x);
}
__device__ __forceinline__ ushort_t f2bf(float f) {
    unsigned int x = __float_as_uint(f);
    unsigned int lsb = (x >> 16) & 1;
    x += 0x7fffu + lsb;   // round-to-nearest-even
    return (ushort_t)(x >> 16);
}

// ---------------------------------------------------------------------------
// Kernel 0: split + transpose W.  W:[1024][64] f32 -> wt{h,l}:[3][64][1024] bf16
// ---------------------------------------------------------------------------
__global__ __launch_bounds__(256) void wsplit_kernel(
    const float* __restrict__ Wq, const float* __restrict__ Wk,
    const float* __restrict__ Wv,
    ushort_t* __restrict__ wth, ushort_t* __restrict__ wtl)
{
    int idx = blockIdx.x * 256 + threadIdx.x;      // [0, 49152)
    int mat = idx >> 14;
    int rem = idx & 16383;
    int c = rem >> 4;
    int h4 = (rem & 15) * 4;
    const float* W = (mat == 0) ? Wq : (mat == 1) ? Wk : Wv;
    float4 u = *(const float4*)(W + (size_t)c * HH + h4);
    float vals[4] = {u.x, u.y, u.z, u.w};
    #pragma unroll
    for (int j = 0; j < 4; j++) {
        ushort_t h = f2bf(vals[j]);
        ushort_t l = f2bf(vals[j] - bf2f(h));
        size_t off = ((size_t)mat * HH + h4 + j) * CC + c;
        wth[off] = h;
        wtl[off] = l;
    }
}

// ---------------------------------------------------------------------------
// Kernel 1: fused q/k/v projection, K-split across 4 waves + LDS reduce.
// grid 1024: block = 16 rows; wave w handles K in [w*256, w*256+256).
// ---------------------------------------------------------------------------
__global__ __launch_bounds__(256) void proj_mfma(
    const float* __restrict__ x,
    const ushort_t* __restrict__ wth, const ushort_t* __restrict__ wtl,
    ushort_t* __restrict__ qh, ushort_t* __restrict__ ql,
    ushort_t* __restrict__ kh, ushort_t* __restrict__ kl,
    ushort_t* __restrict__ vt)
{
    const int tid = threadIdx.x;
    const int lane = tid & 63, wid = tid >> 6;
    const int quad = lane >> 4, l15 = lane & 15;
    const int r0 = blockIdx.x * 16;

    __shared__ float red[4][16][72];   // 18.4 KB (72-f32 stride: 16B-aligned rows)
    __shared__ float tr[64][17];       // 4.3 KB

    f32x4 acc[3][4];
    #pragma unroll
    for (int m = 0; m < 3; m++)
        #pragma unroll
        for (int nt = 0; nt < 4; nt++)
            acc[m][nt] = (f32x4){0.f, 0.f, 0.f, 0.f};

    const float* xrow = x + (size_t)(r0 + l15) * CC;
    const int kbase = wid * 256;

    #pragma unroll 2
    for (int kc = 0; kc < 8; kc++) {
        const int c0 = kbase + kc * 32 + quad * 8;
        float4 u0 = *(const float4*)(xrow + c0);
        float4 u1 = *(const float4*)(xrow + c0 + 4);
        float xv[8] = {u0.x, u0.y, u0.z, u0.w, u1.x, u1.y, u1.z, u1.w};
        bf16x8 xh_, xl_;
        #pragma unroll
        for (int j = 0; j < 8; j++) {
            ushort_t h = f2bf(xv[j]);
            xh_[j] = (short)h;
            xl_[j] = (short)f2bf(xv[j] - bf2f(h));
        }
        #pragma unroll
        for (int mat = 0; mat < 3; mat++)
            #pragma unroll
            for (int nt = 0; nt < 4; nt++) {
                size_t off = ((size_t)mat * HH + nt * 16 + l15) * CC + c0;
                bf16x8 bh = *(const bf16x8*)(wth + off);
                if (mat < 2) {
                    bf16x8 bl = *(const bf16x8*)(wtl + off);
                    acc[mat][nt] = __builtin_amdgcn_mfma_f32_16x16x32_bf16(xl_, bh, acc[mat][nt], 0, 0, 0);
                    acc[mat][nt] = __builtin_amdgcn_mfma_f32_16x16x32_bf16(xh_, bl, acc[mat][nt], 0, 0, 0);
                }
                acc[mat][nt] = __builtin_amdgcn_mfma_f32_16x16x32_bf16(xh_, bh, acc[mat][nt], 0, 0, 0);
            }
    }

    const int row = tid >> 4, c4 = (tid & 15) * 4;
    #pragma unroll
    for (int mat = 0; mat < 3; mat++) {
        if (mat) __syncthreads();         // previous phase's reads done
        #pragma unroll
        for (int nt = 0; nt < 4; nt++)
            #pragma unroll
            for (int r = 0; r < 4; r++)
                red[wid][quad * 4 + r][nt * 16 + l15] = acc[mat][nt][r];
        __syncthreads();

        f32x4 s0 = *(const f32x4*)&red[0][row][c4];
        f32x4 s1 = *(const f32x4*)&red[1][row][c4];
        f32x4 s2 = *(const f32x4*)&red[2][row][c4];
        f32x4 s3 = *(const f32x4*)&red[3][row][c4];
        f32x4 s = s0 + s1 + s2 + s3;

        if (mat < 2) {
            ushort_t hv[4], lv[4];
            #pragma unroll
            for (int j = 0; j < 4; j++) {
                hv[j] = f2bf(s[j]);
                lv[j] = f2bf(s[j] - bf2f(hv[j]));
            }
            size_t off = (size_t)(r0 + row) * HH + c4;
            ushort_t* hp = (mat == 0) ? qh : kh;
            ushort_t* lp = (mat == 0) ? ql : kl;
            *(ushort4*)(hp + off) = make_ushort4(hv[0], hv[1], hv[2], hv[3]);
            *(ushort4*)(lp + off) = make_ushort4(lv[0], lv[1], lv[2], lv[3]);
        } else {
            #pragma unroll
            for (int j = 0; j < 4; j++)
                tr[c4 + j][row] = s[j];
            __syncthreads();
            const int h = tid >> 2, t4 = (tid & 3) * 4;
            const int b = r0 >> 11, tloc = r0 & 2047;
            ushort4 w = make_ushort4(f2bf(tr[h][t4 + 0]), f2bf(tr[h][t4 + 1]),
                                     f2bf(tr[h][t4 + 2]), f2bf(tr[h][t4 + 3]));
            *(ushort4*)(vt + ((size_t)b * HH + h) * TT + tloc + t4) = w;
        }
    }
}

// ---------------------------------------------------------------------------
// Kernel 2: l[b,s] += column sums of exp(qk^T); also stores unnormalized
// P = exp(S) bf16 into triangular-packed tiles. Block 128x128, wave 64x64.
// ---------------------------------------------------------------------------
__global__ __launch_bounds__(256) void colsum_mfma(
    const ushort_t* __restrict__ qh, const ushort_t* __restrict__ ql,
    const ushort_t* __restrict__ kh, const ushort_t* __restrict__ kl,
    float* __restrict__ lsum, ushort_t* __restrict__ Ppack)
{
    const int tc = blockIdx.x, st = blockIdx.y, b = blockIdx.z;
    if (tc < st) return;
    const int tid = threadIdx.x;
    const int lane = tid & 63, wid = tid >> 6;
    const int quad = lane >> 4, l15 = lane & 15;
    const int wy = wid >> 1, wx = wid & 1;
    const int t_base = tc * 128 + wy * 64;
    const int s_base = st * 128 + wx * 64;
    if (t_base < s_base) return;
    const bool needMask = (t_base == s_base);

    __shared__ __align__(16) ushort_t sT[4][64][72];   // 36.9 KB, wave-private

    const size_t boff = (size_t)b * TT * HH;
    const ushort_t* qhb = qh + boff;
    const ushort_t* qlb = ql + boff;
    const ushort_t* khb = kh + boff;
    const ushort_t* klb = kl + boff;

    f32x4 acc[4][4];
    #pragma unroll
    for (int mt = 0; mt < 4; mt++)
        #pragma unroll
        for (int nt = 0; nt < 4; nt++)
            acc[mt][nt] = (f32x4){0.f, 0.f, 0.f, 0.f};

    bf16x8 bH[4][2], bL[4][2];
    #pragma unroll
    for (int nt = 0; nt < 4; nt++)
        #pragma unroll
        for (int ks = 0; ks < 2; ks++) {
            size_t off = (size_t)(s_base + nt * 16 + l15) * HH + ks * 32 + quad * 8;
            bH[nt][ks] = *(const bf16x8*)(khb + off);
            bL[nt][ks] = *(const bf16x8*)(klb + off);
        }

    #pragma unroll
    for (int mt = 0; mt < 4; mt++) {
        bf16x8 aH[2], aL[2];
        #pragma unroll
        for (int ks = 0; ks < 2; ks++) {
            size_t off = (size_t)(t_base + mt * 16 + l15) * HH + ks * 32 + quad * 8;
            aH[ks] = *(const bf16x8*)(qhb + off);
            aL[ks] = *(const bf16x8*)(qlb + off);
        }
        #pragma unroll
        for (int nt = 0; nt < 4; nt++)
            #pragma unroll
            for (int ks = 0; ks < 2; ks++) {
                acc[mt][nt] = __builtin_amdgcn_mfma_f32_16x16x32_bf16(aL[ks], bH[nt][ks], acc[mt][nt], 0, 0, 0);
                acc[mt][nt] = __builtin_amdgcn_mfma_f32_16x16x32_bf16(aH[ks], bL[nt][ks], acc[mt][nt], 0, 0, 0);
                acc[mt][nt] = __builtin_amdgcn_mfma_f32_16x16x32_bf16(aH[ks], bH[nt][ks], acc[mt][nt], 0, 0, 0);
            }
    }

    float cs[4] = {0.f, 0.f, 0.f, 0.f};
    #pragma unroll
    for (int mt = 0; mt < 4; mt++)
        #pragma unroll
        for (int nt = 0; nt < 4; nt++)
            #pragma unroll
            for (int r = 0; r < 4; r++) {
                float e = __expf(acc[mt][nt][r]);
                if (needMask) {
                    int t = t_base + mt * 16 + quad * 4 + r;
                    int s = s_base + nt * 16 + l15;
                    if (t < s) e = 0.f;
                }
                cs[nt] += e;
                sT[wid][mt * 16 + quad * 4 + r][nt * 16 + l15] = f2bf(e);
            }

    #pragma unroll
    for (int nt = 0; nt < 4; nt++) {
        float v = cs[nt];
        v += __shfl_xor(v, 16);
        v += __shfl_xor(v, 32);
        if (quad == 0)
            atomicAdd(lsum + (size_t)b * TT + s_base + nt * 16 + l15, v);
    }

    // store this wave's 64x64 P tile (triangular-packed, row-major)
    const int ti = t_base >> 6, si = s_base >> 6;
    ushort_t* tp = Ppack + (((size_t)b * NTRI + (size_t)(ti * (ti + 1) / 2) + si) << 12);
    #pragma unroll
    for (int i = 0; i < 8; i++) {
        int row = i * 8 + (lane >> 3);
        int c8 = (lane & 7) * 8;
        *(bf16x8*)(tp + row * 64 + c8) = *(const bf16x8*)(&sT[wid][row][c8]);
    }
}

// ---------------------------------------------------------------------------
// Kernel 2b: vts[b][h][t] = vt[b][h][t] / l[b][t]
// ---------------------------------------------------------------------------
__global__ __launch_bounds__(256) void vscale_kernel(
    const ushort_t* __restrict__ vt, const float* __restrict__ lsum,
    ushort_t* __restrict__ vts)
{
    size_t idx4 = ((size_t)blockIdx.x * 256 + threadIdx.x) * 4;
    int t4 = (int)(idx4 & 2047);
    int b = (int)(idx4 >> 17);
    float4 lv = *(const float4*)(lsum + (size_t)b * TT + t4);
    ushort4 vv = *(const ushort4*)(vt + idx4);
    ushort4 o;
    o.x = f2bf(bf2f(vv.x) / lv.x);
    o.y = f2bf(bf2f(vv.y) / lv.y);
    o.z = f2bf(bf2f(vv.z) / lv.z);
    o.w = f2bf(bf2f(vv.w) / lv.w);
    *(ushort4*)(vts + idx4) = o;
}

// ---------------------------------------------------------------------------
// Kernel 3: out = P * vts^T (pure PV GEMM over packed triangular P).
// grid (32 pairs, 8 b). Block: t-tiles p and 63-p (32 rows each), 4 waves
// strided over 64-wide s-chunks. No syncs in hot loop.
// ---------------------------------------------------------------------------
__global__ __launch_bounds__(256) void attn_pv(
    const ushort_t* __restrict__ Ppack, const ushort_t* __restrict__ vts,
    float* __restrict__ out)
{
    const int p = blockIdx.x, b = blockIdx.y;
    const int tid = threadIdx.x;
    const int lane = tid & 63, wid = tid >> 6;
    const int quad = lane >> 4, l15 = lane & 15;

    __shared__ __align__(16) float red[4][2048];   // 32 KB

    const ushort_t* vtb = vts + (size_t)b * HH * TT;

    #pragma unroll
    for (int half = 0; half < 2; half++) {
        const int tileI = half ? (63 - p) : p;
        const int t0 = tileI * 32;
        const int ti = t0 >> 6, trel = t0 & 63;
        const size_t triBase = ((size_t)b * NTRI + (size_t)(ti * (ti + 1) / 2)) << 12;

        f32x4 oacc[2][4];
        #pragma unroll
        for (int mt = 0; mt < 2; mt++)
            #pragma unroll
            for (int nt = 0; nt < 4; nt++)
                oacc[mt][nt] = (f32x4){0.f, 0.f, 0.f, 0.f};

        for (int s0 = wid * 64; s0 <= t0 + 31; s0 += 256) {
            const int si = s0 >> 6;
            const ushort_t* tp = Ppack + triBase + ((size_t)si << 12);
            bf16x8 pa[2][2];
            #pragma unroll
            for (int mt = 0; mt < 2; mt++)
                #pragma unroll
                for (int ks = 0; ks < 2; ks++)
                    pa[mt][ks] = *(const bf16x8*)(tp + (trel + mt * 16 + l15) * 64 + ks * 32 + quad * 8);
            #pragma unroll
            for (int nt = 0; nt < 4; nt++)
                #pragma unroll
                for (int ks = 0; ks < 2; ks++) {
                    bf16x8 vb = *(const bf16x8*)(vtb + (size_t)(nt * 16 + l15) * TT + s0 + ks * 32 + quad * 8);
                    #pragma unroll
                    for (int mt = 0; mt < 2; mt++)
                        oacc[mt][nt] = __builtin_amdgcn_mfma_f32_16x16x32_bf16(pa[mt][ks], vb, oacc[mt][nt], 0, 0, 0);
                }
        }

        __syncthreads();   // red free (prev half's reads done / first entry)
        #pragma unroll
        for (int mt = 0; mt < 2; mt++)
            #pragma unroll
            for (int nt = 0; nt < 4; nt++)
                #pragma unroll
                for (int r = 0; r < 4; r++)
                    red[wid][(mt * 16 + quad * 4 + r) * 64 + nt * 16 + l15] =
                        oacc[mt][nt][r];
        __syncthreads();
        for (int e = tid; e < 2048; e += 256) {
            float s_ = red[0][e] + red[1][e] + red[2][e] + red[3][e];
            out[(size_t)(b * TT + t0 + (e >> 6)) * HH + (e & 63)] = s_;
        }
    }
}

extern "C" void kernel_launch(void* const* d_in, const int* in_sizes, int n_in,
                              void* d_out, int out_size, void* d_ws, size_t ws_size,
                              hipStream_t stream)
{
    const float* x  = (const float*)d_in[0];
    const float* Wq = (const float*)d_in[1];
    const float* Wk = (const float*)d_in[2];
    const float* Wv = (const float*)d_in[3];
    float* out = (float*)d_out;

    const size_t N = (size_t)BB * TT * HH;     // 1,048,576 elements
    ushort_t* qh = (ushort_t*)d_ws;
    ushort_t* ql = qh + N;
    ushort_t* kh = ql + N;
    ushort_t* kl = kh + N;
    ushort_t* vt = kl + N;                     // [b][64][2048] bf16
    ushort_t* vts = vt + N;                    // [b][64][2048] bf16, scaled
    float* lsum = (float*)(vts + N);           // [8][2048]
    ushort_t* wth = (ushort_t*)(lsum + (size_t)BB * TT);   // [3][64][1024]
    ushort_t* wtl = wth + (size_t)3 * HH * CC;
    ushort_t* Ppack = wtl + (size_t)3 * HH * CC;           // 8*528*4096 bf16

    hipMemsetAsync(lsum, 0, (size_t)BB * TT * sizeof(float), stream);
    wsplit_kernel<<<dim3(192), 256, 0, stream>>>(Wq, Wk, Wv, wth, wtl);
    proj_mfma<<<dim3(1024), 256, 0, stream>>>(x, wth, wtl, qh, ql, kh, kl, vt);
    colsum_mfma<<<dim3(16, 16, BB), 256, 0, stream>>>(qh, ql, kh, kl, lsum, Ppack);
    vscale_kernel<<<dim3(1024), 256, 0, stream>>>(vt, lsum, vts);
    attn_pv<<<dim3(32, BB), 256, 0, stream>>>(Ppack, vts, out);
}

// Round 6
// 168.930 us; speedup vs baseline: 3.1895x; 1.3961x over previous
//
#include <hip/hip_runtime.h>
#include <hip/hip_bf16.h>

#define BB 8
#define TT 2048
#define CC 1024
#define HH 64
#define NTRI 528                 // 32*33/2 triangular 64x64 tiles per batch
#define NPB (TT * HH)            // 131072 elems per batch per tensor

typedef unsigned short ushort_t;
typedef __attribute__((ext_vector_type(8))) short bf16x8;
typedef __attribute__((ext_vector_type(4))) float f32x4;

__device__ __forceinline__ float bf2f(ushort_t u) {
    unsigned int x = ((unsigned int)u) << 16;
    return __uint_as_float(x);
}
__device__ __forceinline__ ushort_t f2bf(float f) {
    unsigned int x = __float_as_uint(f);
    unsigned int lsb = (x >> 16) & 1;
    x += 0x7fffu + lsb;   // round-to-nearest-even
    return (ushort_t)(x >> 16);
}

// ---------------------------------------------------------------------------
// Kernel 0: pack weights into MFMA B-fragment records.
// wpack[part(5)][kc(32)][nt(4)][lane(64)][8]; parts: qh,ql,kh,kl,vh.
// record elem j (lane=(quad,l15)): W[c=kc*32+quad*8+j][h=nt*16+l15]
// ---------------------------------------------------------------------------
__global__ __launch_bounds__(256) void wsplit_kernel(
    const float* __restrict__ Wq, const float* __restrict__ Wk,
    const float* __restrict__ Wv, ushort_t* __restrict__ wpack)
{
    int slot = blockIdx.x * 256 + threadIdx.x;   // [0, 40960)
    int rec = slot >> 6, lane = slot & 63;
    int quad = lane >> 4, l15 = lane & 15;
    int part = rec >> 7;
    int r2 = rec & 127;
    int kc = r2 >> 2, nt = r2 & 3;
    const float* W = (part < 2) ? Wq : (part < 4) ? Wk : Wv;
    bool lo = (part < 4) && (part & 1);
    bf16x8 o;
    #pragma unroll
    for (int j = 0; j < 8; j++) {
        int c = kc * 32 + quad * 8 + j;
        float w = W[(size_t)c * HH + nt * 16 + l15];
        ushort_t h = f2bf(w);
        o[j] = (short)(lo ? f2bf(w - bf2f(h)) : h);
    }
    *(bf16x8*)(wpack + (size_t)rec * 512 + lane * 8) = o;
}

// ---------------------------------------------------------------------------
// Kernel 1: fused q/k/v projection. Block = 32 M rows, grid 512.
// Wave (mtW, ntH): m-tile mtW, n-tiles {2*ntH, 2*ntH+1} of each of q,k,v.
// Emits qh/ql/kh/kl packed (A/B-frag order) and v packed (PV B-frag order).
// ---------------------------------------------------------------------------
__global__ __launch_bounds__(256) void proj_mfma(
    const float* __restrict__ x, const ushort_t* __restrict__ wpack,
    ushort_t* __restrict__ qpk, ushort_t* __restrict__ qpl,
    ushort_t* __restrict__ kpk, ushort_t* __restrict__ kpl,
    ushort_t* __restrict__ vpk)
{
    const int tid = threadIdx.x;
    const int lane = tid & 63, wid = tid >> 6;
    const int quad = lane >> 4, l15 = lane & 15;
    const int r0 = blockIdx.x * 32;
    const int mtW = wid >> 1, ntH = wid & 1;
    const int nt0 = ntH * 2;

    __shared__ __align__(16) unsigned char smem[3 * 32 * 72 * 4];  // 27.6 KB
    ushort_t* xh = (ushort_t*)smem;                    // [32][72] bf16
    ushort_t* xl = (ushort_t*)(smem + 32 * 72 * 2);
    float* sC = (float*)smem;                          // [3][32][72] f32 (after K-loop)

    f32x4 acc[3][2];
    #pragma unroll
    for (int p = 0; p < 3; p++)
        #pragma unroll
        for (int g = 0; g < 2; g++)
            acc[p][g] = (f32x4){0.f, 0.f, 0.f, 0.f};

    // prefetch first x tile
    float4 cur[2];
    #pragma unroll
    for (int i = 0; i < 2; i++) {
        int slot = tid + i * 256;
        int row = slot >> 4, c4 = (slot & 15) * 4;
        cur[i] = *(const float4*)(x + (size_t)(r0 + row) * CC + c4);
    }

    for (int bk = 0; bk < 16; bk++) {
        if (bk) __syncthreads();           // previous tile's readers done
        #pragma unroll
        for (int i = 0; i < 2; i++) {
            int slot = tid + i * 256;
            int row = slot >> 4, c4 = (slot & 15) * 4;
            float vv[4] = {cur[i].x, cur[i].y, cur[i].z, cur[i].w};
            ushort4 h4, l4;
            ushort_t* hp = (ushort_t*)&h4;
            ushort_t* lp = (ushort_t*)&l4;
            #pragma unroll
            for (int j = 0; j < 4; j++) {
                ushort_t h = f2bf(vv[j]);
                hp[j] = h;
                lp[j] = f2bf(vv[j] - bf2f(h));
            }
            *(ushort4*)(xh + row * 72 + c4) = h4;
            *(ushort4*)(xl + row * 72 + c4) = l4;
        }
        __syncthreads();
        if (bk < 15) {                      // prefetch next tile (overlaps MFMA)
            #pragma unroll
            for (int i = 0; i < 2; i++) {
                int slot = tid + i * 256;
                int row = slot >> 4, c4 = (slot & 15) * 4;
                cur[i] = *(const float4*)(x + (size_t)(r0 + row) * CC + (bk + 1) * 64 + c4);
            }
        }
        #pragma unroll
        for (int c = 0; c < 2; c++) {
            const int kc = bk * 2 + c;
            bf16x8 aH = *(const bf16x8*)(xh + (mtW * 16 + l15) * 72 + c * 32 + quad * 8);
            bf16x8 aL = *(const bf16x8*)(xl + (mtW * 16 + l15) * 72 + c * 32 + quad * 8);
            #pragma unroll
            for (int g = 0; g < 2; g++) {
                const int nt = nt0 + g;
                const size_t lb8 = (size_t)lane * 8;
                bf16x8 bQh = *(const bf16x8*)(wpack + (((size_t)(0 * 32 + kc) * 4 + nt) * 512) + lb8);
                bf16x8 bQl = *(const bf16x8*)(wpack + (((size_t)(1 * 32 + kc) * 4 + nt) * 512) + lb8);
                bf16x8 bKh = *(const bf16x8*)(wpack + (((size_t)(2 * 32 + kc) * 4 + nt) * 512) + lb8);
                bf16x8 bKl = *(const bf16x8*)(wpack + (((size_t)(3 * 32 + kc) * 4 + nt) * 512) + lb8);
                bf16x8 bVh = *(const bf16x8*)(wpack + (((size_t)(4 * 32 + kc) * 4 + nt) * 512) + lb8);
                acc[0][g] = __builtin_amdgcn_mfma_f32_16x16x32_bf16(aL, bQh, acc[0][g], 0, 0, 0);
                acc[0][g] = __builtin_amdgcn_mfma_f32_16x16x32_bf16(aH, bQl, acc[0][g], 0, 0, 0);
                acc[0][g] = __builtin_amdgcn_mfma_f32_16x16x32_bf16(aH, bQh, acc[0][g], 0, 0, 0);
                acc[1][g] = __builtin_amdgcn_mfma_f32_16x16x32_bf16(aL, bKh, acc[1][g], 0, 0, 0);
                acc[1][g] = __builtin_amdgcn_mfma_f32_16x16x32_bf16(aH, bKl, acc[1][g], 0, 0, 0);
                acc[1][g] = __builtin_amdgcn_mfma_f32_16x16x32_bf16(aH, bKh, acc[1][g], 0, 0, 0);
                acc[2][g] = __builtin_amdgcn_mfma_f32_16x16x32_bf16(aH, bVh, acc[2][g], 0, 0, 0);
            }
        }
    }
    __syncthreads();   // xh/xl dead; smem becomes sC

    #pragma unroll
    for (int p = 0; p < 3; p++)
        #pragma unroll
        for (int g = 0; g < 2; g++) {
            const int nt = nt0 + g;
            #pragma unroll
            for (int r = 0; r < 4; r++)
                sC[(p * 32 + mtW * 16 + quad * 4 + r) * 72 + nt * 16 + l15] = acc[p][g][r];
        }
    __syncthreads();

    const int b = r0 >> 11;
    // emit q,k packed hi/lo: rec = (mtR, ksR); elem j = C[mtR*16+l15][ksR*32+quad*8+j]
    {
        const int rec = tid >> 6;
        const int mtR = rec >> 1, ksR = rec & 1;
        const int gt = ((r0 & 2047) >> 4) + mtR;
        const size_t dst = (size_t)b * NPB + (((size_t)ksR * 128 + gt) * 64 + lane) * 8;
        #pragma unroll
        for (int p = 0; p < 2; p++) {
            const float* src = &sC[(p * 32 + mtR * 16 + l15) * 72 + ksR * 32 + quad * 8];
            f32x4 v0 = *(const f32x4*)src;
            f32x4 v1 = *(const f32x4*)(src + 4);
            bf16x8 h8, l8;
            #pragma unroll
            for (int j = 0; j < 4; j++) {
                ushort_t h = f2bf(v0[j]);
                h8[j] = (short)h;
                l8[j] = (short)f2bf(v0[j] - bf2f(h));
            }
            #pragma unroll
            for (int j = 0; j < 4; j++) {
                ushort_t h = f2bf(v1[j]);
                h8[4 + j] = (short)h;
                l8[4 + j] = (short)f2bf(v1[j] - bf2f(h));
            }
            *(bf16x8*)((p == 0 ? qpk : kpk) + dst) = h8;
            *(bf16x8*)((p == 0 ? qpl : kpl) + dst) = l8;
        }
    }
    // emit v packed (PV B-frag order, unscaled): elem j = v[s=quad*8+j][h=nt*16+l15]
    {
        const int nt = tid >> 6;
        const int scL = (r0 & 2047) >> 5;
        bf16x8 o;
        #pragma unroll
        for (int j = 0; j < 8; j++)
            o[j] = (short)f2bf(sC[(2 * 32 + quad * 8 + j) * 72 + nt * 16 + l15]);
        *(bf16x8*)(vpk + (size_t)b * NPB + (((size_t)scL * 4 + nt) * 64 + lane) * 8) = o;
    }
}

// ---------------------------------------------------------------------------
// Kernel 2: l[b,s] += column sums of exp(qk^T); stores P = exp(S) bf16 in
// PV-A-fragment-packed triangular tiles. Block 128x128, wave 64x64.
// ---------------------------------------------------------------------------
__global__ __launch_bounds__(256) void colsum_mfma(
    const ushort_t* __restrict__ qpk, const ushort_t* __restrict__ qpl,
    const ushort_t* __restrict__ kpk, const ushort_t* __restrict__ kpl,
    float* __restrict__ lsum, ushort_t* __restrict__ Ppack)
{
    const int tc = blockIdx.x, st = blockIdx.y, b = blockIdx.z;
    if (tc < st) return;
    const int tid = threadIdx.x;
    const int lane = tid & 63, wid = tid >> 6;
    const int quad = lane >> 4, l15 = lane & 15;
    const int wy = wid >> 1, wx = wid & 1;
    const int t_base = tc * 128 + wy * 64;
    const int s_base = st * 128 + wx * 64;
    if (t_base < s_base) return;
    const bool needMask = (t_base == s_base);

    __shared__ __align__(16) ushort_t sT[4][64][72];   // 36.9 KB, wave-private

    const size_t bq = (size_t)b * NPB;
    const size_t lb8 = (size_t)lane * 8;

    // B preload: k fragments (packed layout = A layout)
    bf16x8 bH[4][2], bL[4][2];
    #pragma unroll
    for (int nt = 0; nt < 4; nt++)
        #pragma unroll
        for (int ks = 0; ks < 2; ks++) {
            const size_t off = bq + (((size_t)ks * 128 + (s_base >> 4) + nt) * 64) * 8 + lb8;
            bH[nt][ks] = *(const bf16x8*)(kpk + off);
            bL[nt][ks] = *(const bf16x8*)(kpl + off);
        }

    float cs[4] = {0.f, 0.f, 0.f, 0.f};

    #pragma unroll
    for (int mt = 0; mt < 4; mt++) {
        bf16x8 aH[2], aL[2];
        #pragma unroll
        for (int ks = 0; ks < 2; ks++) {
            const size_t off = bq + (((size_t)ks * 128 + (t_base >> 4) + mt) * 64) * 8 + lb8;
            aH[ks] = *(const bf16x8*)(qpk + off);
            aL[ks] = *(const bf16x8*)(qpl + off);
        }
        f32x4 acc[4];
        #pragma unroll
        for (int nt = 0; nt < 4; nt++)
            acc[nt] = (f32x4){0.f, 0.f, 0.f, 0.f};
        #pragma unroll
        for (int nt = 0; nt < 4; nt++)
            #pragma unroll
            for (int ks = 0; ks < 2; ks++) {
                acc[nt] = __builtin_amdgcn_mfma_f32_16x16x32_bf16(aL[ks], bH[nt][ks], acc[nt], 0, 0, 0);
                acc[nt] = __builtin_amdgcn_mfma_f32_16x16x32_bf16(aH[ks], bL[nt][ks], acc[nt], 0, 0, 0);
                acc[nt] = __builtin_amdgcn_mfma_f32_16x16x32_bf16(aH[ks], bH[nt][ks], acc[nt], 0, 0, 0);
            }
        #pragma unroll
        for (int nt = 0; nt < 4; nt++)
            #pragma unroll
            for (int r = 0; r < 4; r++) {
                float e = __expf(acc[nt][r]);
                if (needMask) {
                    int t = mt * 16 + quad * 4 + r;
                    int s = nt * 16 + l15;
                    if (t < s) e = 0.f;
                }
                cs[nt] += e;
                sT[wid][mt * 16 + quad * 4 + r][nt * 16 + l15] = f2bf(e);
            }
    }

    #pragma unroll
    for (int nt = 0; nt < 4; nt++) {
        float v = cs[nt];
        v += __shfl_xor(v, 16);
        v += __shfl_xor(v, 32);
        if (quad == 0)
            atomicAdd(lsum + (size_t)b * TT + s_base + nt * 16 + l15, v);
    }

    // emit P tile as 8 A-frag records: rec=(mtP,ksP), elem j = P[mtP*16+l15][ksP*32+quad*8+j]
    const int ti = t_base >> 6, si = s_base >> 6;
    ushort_t* tp = Ppack + ((size_t)b * NTRI + (size_t)(ti * (ti + 1) / 2) + si) * 4096;
    #pragma unroll
    for (int rec = 0; rec < 8; rec++) {
        const int mtP = rec >> 1, ksP = rec & 1;
        bf16x8 v8 = *(const bf16x8*)&sT[wid][mtP * 16 + l15][ksP * 32 + quad * 8];
        *(bf16x8*)(tp + (size_t)rec * 512 + lb8) = v8;
    }
}

// ---------------------------------------------------------------------------
// Kernel 2b: scale packed v records by 1/l[s]  (s = sc*32 + quad*8 + j)
// ---------------------------------------------------------------------------
__global__ __launch_bounds__(256) void vscale_kernel(
    const ushort_t* __restrict__ vpk, const float* __restrict__ lsum,
    ushort_t* __restrict__ vps)
{
    size_t slot = (size_t)blockIdx.x * 256 + threadIdx.x;   // 131072 slots
    int lane = (int)(slot & 63);
    int quad = lane >> 4;
    int sc_b = (int)(slot >> 8);          // b*64 + sc
    int b = sc_b >> 6, sc = sc_b & 63;
    bf16x8 in = *(const bf16x8*)(vpk + slot * 8);
    const float* lp = lsum + (size_t)b * TT + sc * 32 + quad * 8;
    float4 l0 = *(const float4*)lp;
    float4 l1 = *(const float4*)(lp + 4);
    float li[8] = {l0.x, l0.y, l0.z, l0.w, l1.x, l1.y, l1.z, l1.w};
    bf16x8 o;
    #pragma unroll
    for (int j = 0; j < 8; j++)
        o[j] = (short)f2bf(bf2f((ushort_t)in[j]) / li[j]);
    *(bf16x8*)(vps + slot * 8) = o;
}

// ---------------------------------------------------------------------------
// Kernel 3: out = P * vs^T from packed fragments. grid (32 pairs, 8 b).
// Block: t-tiles p and 63-p (32 rows each); 4 waves stride s-chunks.
// ---------------------------------------------------------------------------
__global__ __launch_bounds__(256) void attn_pv(
    const ushort_t* __restrict__ Ppack, const ushort_t* __restrict__ vps,
    float* __restrict__ out)
{
    const int p = blockIdx.x, b = blockIdx.y;
    const int tid = threadIdx.x;
    const int lane = tid & 63, wid = tid >> 6;
    const int quad = lane >> 4, l15 = lane & 15;
    const size_t lb8 = (size_t)lane * 8;

    __shared__ __align__(16) float red[4][2048];   // 32 KB

    const ushort_t* vb_ = vps + (size_t)b * NPB;

    #pragma unroll
    for (int half = 0; half < 2; half++) {
        const int tileI = half ? (63 - p) : p;
        const int t0 = tileI * 32;
        const int ti = t0 >> 6, trel16 = (t0 & 63) >> 4;   // 0 or 2
        const size_t triBase = ((size_t)b * NTRI + (size_t)(ti * (ti + 1) / 2)) * 4096;

        f32x4 oacc[2][4];
        #pragma unroll
        for (int mt = 0; mt < 2; mt++)
            #pragma unroll
            for (int nt = 0; nt < 4; nt++)
                oacc[mt][nt] = (f32x4){0.f, 0.f, 0.f, 0.f};

        for (int s0 = wid * 64; s0 <= t0 + 31; s0 += 256) {
            const int si = s0 >> 6;
            const ushort_t* tp = Ppack + triBase + (size_t)si * 4096;
            bf16x8 pa[2][2];
            #pragma unroll
            for (int mt = 0; mt < 2; mt++)
                #pragma unroll
                for (int ks = 0; ks < 2; ks++)
                    pa[mt][ks] = *(const bf16x8*)(tp + (size_t)((trel16 + mt) * 2 + ks) * 512 + lb8);
            #pragma unroll
            for (int ks = 0; ks < 2; ks++)
                #pragma unroll
                for (int nt = 0; nt < 4; nt++) {
                    bf16x8 vb = *(const bf16x8*)(vb_ + (((size_t)(s0 >> 5) + ks) * 4 + nt) * 512 + lb8);
                    #pragma unroll
                    for (int mt = 0; mt < 2; mt++)
                        oacc[mt][nt] = __builtin_amdgcn_mfma_f32_16x16x32_bf16(pa[mt][ks], vb, oacc[mt][nt], 0, 0, 0);
                }
        }

        __syncthreads();
        #pragma unroll
        for (int mt = 0; mt < 2; mt++)
            #pragma unroll
            for (int nt = 0; nt < 4; nt++)
                #pragma unroll
                for (int r = 0; r < 4; r++)
                    red[wid][(mt * 16 + quad * 4 + r) * 64 + nt * 16 + l15] =
                        oacc[mt][nt][r];
        __syncthreads();
        for (int e = tid; e < 2048; e += 256) {
            float s_ = red[0][e] + red[1][e] + red[2][e] + red[3][e];
            out[(size_t)(b * TT + t0 + (e >> 6)) * HH + (e & 63)] = s_;
        }
        __syncthreads();
    }
}

extern "C" void kernel_launch(void* const* d_in, const int* in_sizes, int n_in,
                              void* d_out, int out_size, void* d_ws, size_t ws_size,
                              hipStream_t stream)
{
    const float* x  = (const float*)d_in[0];
    const float* Wq = (const float*)d_in[1];
    const float* Wk = (const float*)d_in[2];
    const float* Wv = (const float*)d_in[3];
    float* out = (float*)d_out;

    const size_t N = (size_t)BB * TT * HH;     // 1,048,576
    ushort_t* qpk = (ushort_t*)d_ws;
    ushort_t* qpl = qpk + N;
    ushort_t* kpk = qpl + N;
    ushort_t* kpl = kpk + N;
    ushort_t* vpk = kpl + N;
    ushort_t* vps = vpk + N;
    float* lsum = (float*)(vps + N);                        // [8][2048]
    ushort_t* wpack = (ushort_t*)(lsum + (size_t)BB * TT);  // 327,680 elems
    ushort_t* Ppack = wpack + (size_t)5 * 32 * 4 * 512;     // 17,301,504 elems

    hipMemsetAsync(lsum, 0, (size_t)BB * TT * sizeof(float), stream);
    wsplit_kernel<<<dim3(160), 256, 0, stream>>>(Wq, Wk, Wv, wpack);
    proj_mfma<<<dim3(512), 256, 0, stream>>>(x, wpack, qpk, qpl, kpk, kpl, vpk);
    colsum_mfma<<<dim3(16, 16, BB), 256, 0, stream>>>(qpk, qpl, kpk, kpl, lsum, Ppack);
    vscale_kernel<<<dim3(512), 256, 0, stream>>>(vpk, lsum, vps);
    attn_pv<<<dim3(32, BB), 256, 0, stream>>>(Ppack, vps, out);
}